// Round 7
// baseline (200.300 us; speedup 1.0000x reference)
//
#include <hip/hip_runtime.h>

typedef short v8s __attribute__((ext_vector_type(8)));
typedef float v4f __attribute__((ext_vector_type(4)));
typedef unsigned short u16;

#define NSEQ 2048
#define CDIM 768
#define NH   16
#define DH   48
#define DP   64
#define MROWS 4096      // B*N
#define N3C  2304
#define BH   32         // B*H

#if __has_builtin(__builtin_amdgcn_exp2f)
#define EXP2(x) __builtin_amdgcn_exp2f(x)
#else
#define EXP2(x) exp2f(x)
#endif
#if __has_builtin(__builtin_amdgcn_rcpf)
#define RCP(x) __builtin_amdgcn_rcpf(x)
#else
#define RCP(x) (1.0f/(x))
#endif

__device__ __forceinline__ u16 f2bf(float f){
  unsigned u = __float_as_uint(f);
  u += 0x7FFFu + ((u>>16)&1u);      // RNE; inputs finite
  return (u16)(u>>16);
}

__device__ __forceinline__ void load_lds16(const u16* g, u16* l){
  __builtin_amdgcn_global_load_lds((const __attribute__((address_space(1))) void*)g,
                                   (__attribute__((address_space(3))) void*)l, 16, 0, 0);
}

// ---------------- K0a: fp32 -> bf16 for x, qkv_w, proj_w (contiguous in ws) ----------------
#define XN8  (MROWS*CDIM/8)
#define WN8  (N3C*CDIM/8)
#define PN8  (CDIM*CDIM/8)
__global__ __launch_bounds__(256) void convert_all(const float* __restrict__ x, const float* __restrict__ w,
                                                   const float* __restrict__ pw, u16* __restrict__ dst){
  int i = blockIdx.x*256 + threadIdx.x;
  if (i >= XN8 + WN8 + PN8) return;
  const float* src;
  if (i < XN8)            src = x  + (size_t)i*8;
  else if (i < XN8+WN8)   src = w  + (size_t)(i - XN8)*8;
  else                    src = pw + (size_t)(i - XN8 - WN8)*8;
  v4f f0 = ((const v4f*)src)[0];
  v4f f1 = ((const v4f*)src)[1];
  v8s o;
#pragma unroll
  for (int j = 0; j < 4; j++) ((u16*)&o)[j]   = f2bf(f0[j]);
#pragma unroll
  for (int j = 0; j < 4; j++) ((u16*)&o)[4+j] = f2bf(f1[j]);
  ((v8s*)dst)[i] = o;
}

// ---------------- K0b: zero Q/K pads; V pad row d=48 = 1.0 (rowsum trick), 49..63 = 0 ----------------
__global__ __launch_bounds__(256) void zero_pads(u16* __restrict__ q, u16* __restrict__ k,
                                                 u16* __restrict__ v){
  int idx = blockIdx.x*256 + threadIdx.x;      // 512 blocks -> 131072 threads
  v8s z = (v8s){0,0,0,0,0,0,0,0};
  int r = idx >> 1, half = idx & 1;            // Q/K: 65536 rows, 2x16B pad per row
  *(v8s*)(q + (size_t)r*DP + DH + half*8) = z;
  *(v8s*)(k + (size_t)r*DP + DH + half*8) = z;
  int bh = idx >> 12, i = idx & 4095;          // V: [bh][48..63][2048]
  int row = i >> 8, off = i & 255;
  const short one = (short)0x3F80;             // bf16 1.0
  v8s val = (row == 0) ? (v8s){one,one,one,one,one,one,one,one} : z;
  *(v8s*)(v + ((size_t)(bh*DP + DH + row))*NSEQ + off*8) = val;
}

// ================= K1: qkv GEMM, m97 structure =================
__global__ __launch_bounds__(256) void qkv_gemm(const u16* __restrict__ x, const u16* __restrict__ w,
                                                const float* __restrict__ bias,
                                                u16* __restrict__ q, u16* __restrict__ k, u16* __restrict__ v){
  __shared__ __align__(16) u16 As[128*32];
  __shared__ __align__(16) u16 Bs[128*32];
  const int wave = threadIdx.x >> 6;
  const int lane = threadIdx.x & 63;
  const int l15  = lane & 15;
  const int quad = lane >> 4;
  const int wm = wave & 1, wn = wave >> 1;
  const int m0 = blockIdx.x*128, n0 = blockIdx.y*128;

  const int srow = lane >> 2;
  const int sg   = (lane & 3) ^ ((lane >> 3) & 3);
  const int sgoff = sg*8;

  v4f acc[4][4];
#pragma unroll
  for (int i = 0; i < 4; i++)
#pragma unroll
    for (int j = 0; j < 4; j++) acc[i][j] = (v4f){0.f,0.f,0.f,0.f};

  const int sig = (l15 >> 1) & 3;

  for (int kt = 0; kt < CDIM/32; kt++){
    const int k0 = kt*32;
    __syncthreads();
#pragma unroll
    for (int j = 0; j < 2; j++){
      int c = wave*2 + j;
      int r = c*16 + srow;
      load_lds16(x + (size_t)(m0 + r)*CDIM + k0 + sgoff, &As[c*512]);
      load_lds16(w + (size_t)(n0 + r)*CDIM + k0 + sgoff, &Bs[c*512]);
    }
    __syncthreads();

    v8s af[4], bf[4];
#pragma unroll
    for (int t = 0; t < 4; t++){
      int ra = wm*64 + t*16 + l15;
      af[t] = *(const v8s*)(&As[ra*32 + ((quad ^ sig)<<3)]);
      int rb = wn*64 + t*16 + l15;
      bf[t] = *(const v8s*)(&Bs[rb*32 + ((quad ^ sig)<<3)]);
    }
#pragma unroll
    for (int ti = 0; ti < 4; ti++)
#pragma unroll
      for (int tj = 0; tj < 4; tj++)
        acc[ti][tj] = __builtin_amdgcn_mfma_f32_16x16x32_bf16(af[ti], bf[tj], acc[ti][tj], 0, 0, 0);
  }

  const float QS = 0.2082540589f;   // 1/sqrt(48) * log2(e)
#pragma unroll
  for (int tj = 0; tj < 4; tj++){
    const int c = n0 + wn*64 + tj*16 + l15;
    const float bv = bias[c];
    const int t = c / CDIM;
    const int rem = c - t*CDIM;
    const int h = rem / DH;
    const int d = rem - h*DH;
#pragma unroll
    for (int ti = 0; ti < 4; ti++){
#pragma unroll
      for (int r = 0; r < 4; r++){
        int m = m0 + wm*64 + ti*16 + quad*4 + r;
        int b_ = m >> 11;
        int n  = m & (NSEQ-1);
        float val = acc[ti][tj][r] + bv;
        if (t == 0) val *= QS;
        u16 o  = f2bf(val);
        int bhn = b_*NH + h;
        if (t == 0)      q[((size_t)bhn*NSEQ + n)*DP + d] = o;
        else if (t == 1) k[((size_t)bhn*NSEQ + n)*DP + d] = o;
        else             v[((size_t)bhn*DP + d)*NSEQ + n] = o;
      }
    }
  }
}

// ---------------- K2: flash attention, 2 Q-strips (32 rows) per wave ----------------
// K/V fragments read once from LDS, used for both strips -> ~half LDS read bytes per element.
__global__ __launch_bounds__(256) void attn(const u16* __restrict__ q, const u16* __restrict__ k,
                                            const u16* __restrict__ v, u16* __restrict__ y){
  __shared__ __align__(16) u16 Kl[64*64];       // [key][d], XOR-swizzled 16B granules
  __shared__ __align__(16) u16 Vl[64*64];       // [d][key], XOR-swizzled; d=48 row == 1.0
  __shared__ __align__(16) u16 Pl[4][32*64];    // per-wave P (32 rows), XOR-swizzled
  const int bh = blockIdx.x;
  const int qt = blockIdx.y;                    // 128-row Q tile
  const int wave = threadIdx.x >> 6;
  const int lane = threadIdx.x & 63;
  const int l15  = lane & 15;
  const int quad = lane >> 4;
  const u16* qb = q + (size_t)bh*NSEQ*DP;
  const u16* kb = k + (size_t)bh*NSEQ*DP;
  const u16* vb = v + (size_t)bh*DP*NSEQ;
  const int qm = qt*128 + wave*32;              // first of 32 rows owned by this wave

  v8s qf[2][2];                                 // [strip][ks]
#pragma unroll
  for (int si = 0; si < 2; si++)
#pragma unroll
    for (int ks = 0; ks < 2; ks++)
      qf[si][ks] = *(const v8s*)(qb + (size_t)(qm + si*16 + l15)*DP + ks*32 + quad*8);

  v4f o[2][4];                   // [strip][dt]; dt 3 col 0 = rowsum
#pragma unroll
  for (int si = 0; si < 2; si++)
#pragma unroll
    for (int i = 0; i < 4; i++) o[si][i] = (v4f){0.f,0.f,0.f,0.f};

  // kt-invariant P-write offsets (strip adds si*1024; row&7 is si-independent)
  int pwoff[4][4];
#pragma unroll
  for (int nt = 0; nt < 4; nt++)
#pragma unroll
    for (int r = 0; r < 4; r++){
      int row = quad*4 + r;
      int col = nt*16 + l15;
      pwoff[nt][r] = row*64 + ((((col>>3) ^ (row&7))<<3) | (col&7));
    }

  for (int kt = 0; kt < NSEQ/64; kt++){
    __syncthreads();
    {
      const int t = threadIdx.x;
#pragma unroll
      for (int p = 0; p < 2; p++){
        int ci  = t + p*256;
        int row = ci >> 3;
        int off = ci & 7;
        v8s kd = *(const v8s*)(kb + (size_t)(kt*64 + row)*DP + off*8);
        *(v8s*)(&Kl[row*64 + ((off ^ (row&7))<<3)]) = kd;
        v8s vd = *(const v8s*)(vb + (size_t)row*NSEQ + kt*64 + off*8);
        *(v8s*)(&Vl[row*64 + ((off ^ (row&7))<<3)]) = vd;
      }
    }
    __syncthreads();

    // S = Q K^T for both strips; K fragment read once
    v4f s[2][4];
#pragma unroll
    for (int nt = 0; nt < 4; nt++){
      s[0][nt] = (v4f){0.f,0.f,0.f,0.f};
      s[1][nt] = (v4f){0.f,0.f,0.f,0.f};
#pragma unroll
      for (int ks = 0; ks < 2; ks++){
        int rrow = nt*16 + l15;
        v8s bf = *(const v8s*)(&Kl[rrow*64 + (((ks*4+quad) ^ (rrow&7))<<3)]);
        s[0][nt] = __builtin_amdgcn_mfma_f32_16x16x32_bf16(qf[0][ks], bf, s[0][nt], 0, 0, 0);
        s[1][nt] = __builtin_amdgcn_mfma_f32_16x16x32_bf16(qf[1][ks], bf, s[1][nt], 0, 0, 0);
      }
    }

    // P = exp2(S) -> LDS (bf16)
#pragma unroll
    for (int si = 0; si < 2; si++)
#pragma unroll
      for (int nt = 0; nt < 4; nt++)
#pragma unroll
        for (int r = 0; r < 4; r++)
          Pl[wave][si*1024 + pwoff[nt][r]] = f2bf(EXP2(s[si][nt][r]));

    // O += P V ; V fragment read once, used for both strips
    v8s pa[2][2];
#pragma unroll
    for (int si = 0; si < 2; si++)
#pragma unroll
      for (int ks = 0; ks < 2; ks++){
        int ga = ks*4 + quad;
        pa[si][ks] = *(const v8s*)(&Pl[wave][si*1024 + l15*64 + ((ga ^ (l15&7))<<3)]);
      }
#pragma unroll
    for (int dt = 0; dt < 4; dt++){
#pragma unroll
      for (int ks = 0; ks < 2; ks++){
        int row = dt*16 + l15;
        v8s vf = *(const v8s*)(&Vl[row*64 + (((ks*4+quad) ^ (row&7))<<3)]);
        o[0][dt] = __builtin_amdgcn_mfma_f32_16x16x32_bf16(pa[0][ks], vf, o[0][dt], 0, 0, 0);
        o[1][dt] = __builtin_amdgcn_mfma_f32_16x16x32_bf16(pa[1][ks], vf, o[1][dt], 0, 0, 0);
      }
    }
  }

  const int b_ = bh / NH, h = bh % NH;
#pragma unroll
  for (int si = 0; si < 2; si++){
#pragma unroll
    for (int r = 0; r < 4; r++){
      float lsum = __shfl(o[si][3][r], quad << 4);   // rowsum at l15==0 of dt=3
      float inv  = RCP(lsum);
      int rowg = b_*NSEQ + qm + si*16 + quad*4 + r;
#pragma unroll
      for (int dt = 0; dt < 3; dt++)
        y[(size_t)rowg*CDIM + h*DH + dt*16 + l15] = f2bf(o[si][dt][r]*inv);
    }
  }
}

// ================= K3: proj GEMM, m97 structure, 64x128 tile =================
__global__ __launch_bounds__(256) void proj_gemm(const u16* __restrict__ y, const u16* __restrict__ w,
                                                 const float* __restrict__ bias, float* __restrict__ out){
  __shared__ __align__(16) u16 As[64*32];
  __shared__ __align__(16) u16 Bs[128*32];
  const int wave = threadIdx.x >> 6;
  const int lane = threadIdx.x & 63;
  const int l15  = lane & 15;
  const int quad = lane >> 4;
  const int wm = wave & 1, wn = wave >> 1;
  const int m0 = blockIdx.x*64, n0 = blockIdx.y*128;

  const int srow = lane >> 2;
  const int sg   = (lane & 3) ^ ((lane >> 3) & 3);
  const int sgoff = sg*8;

  v4f acc[2][4];
#pragma unroll
  for (int i = 0; i < 2; i++)
#pragma unroll
    for (int j = 0; j < 4; j++) acc[i][j] = (v4f){0.f,0.f,0.f,0.f};

  const int sig = (l15 >> 1) & 3;

  for (int kt = 0; kt < CDIM/32; kt++){
    const int k0 = kt*32;
    __syncthreads();
    {
      int rA = wave*16 + srow;
      load_lds16(y + (size_t)(m0 + rA)*CDIM + k0 + sgoff, &As[wave*512]);
#pragma unroll
      for (int j = 0; j < 2; j++){
        int c = wave*2 + j;
        int rB = c*16 + srow;
        load_lds16(w + (size_t)(n0 + rB)*CDIM + k0 + sgoff, &Bs[c*512]);
      }
    }
    __syncthreads();

    v8s af[2], bf[4];
#pragma unroll
    for (int t = 0; t < 2; t++){
      int ra = wm*32 + t*16 + l15;
      af[t] = *(const v8s*)(&As[ra*32 + ((quad ^ sig)<<3)]);
    }
#pragma unroll
    for (int t = 0; t < 4; t++){
      int rb = wn*64 + t*16 + l15;
      bf[t] = *(const v8s*)(&Bs[rb*32 + ((quad ^ sig)<<3)]);
    }
#pragma unroll
    for (int ti = 0; ti < 2; ti++)
#pragma unroll
      for (int tj = 0; tj < 4; tj++)
        acc[ti][tj] = __builtin_amdgcn_mfma_f32_16x16x32_bf16(af[ti], bf[tj], acc[ti][tj], 0, 0, 0);
  }

#pragma unroll
  for (int tj = 0; tj < 4; tj++){
    const int c = n0 + wn*64 + tj*16 + l15;
    const float bv = bias[c];
#pragma unroll
    for (int ti = 0; ti < 2; ti++){
#pragma unroll
      for (int r = 0; r < 4; r++){
        int m = m0 + wm*32 + ti*16 + quad*4 + r;
        out[(size_t)m*CDIM + c] = acc[ti][tj][r] + bv;
      }
    }
  }
}

extern "C" void kernel_launch(void* const* d_in, const int* in_sizes, int n_in,
                              void* d_out, int out_size, void* d_ws, size_t ws_size,
                              hipStream_t stream){
  const float* x      = (const float*)d_in[0];
  const float* qkv_w  = (const float*)d_in[1];
  const float* qkv_b  = (const float*)d_in[2];
  const float* proj_w = (const float*)d_in[3];
  const float* proj_b = (const float*)d_in[4];
  float* out = (float*)d_out;

  // ws layout (u16 units) — xb/wb/pwb contiguous for the fused convert
  u16* xb  = (u16*)d_ws;                         // [4096][768] bf16
  u16* wb  = xb  + (size_t)MROWS*CDIM;           // [2304][768] bf16
  u16* pwb = wb  + (size_t)N3C*CDIM;             // [768][768]  bf16
  u16* q   = pwb + (size_t)CDIM*CDIM;            // [BH][NSEQ][DP]
  u16* k   = q + (size_t)BH*NSEQ*DP;
  u16* v   = k + (size_t)BH*NSEQ*DP;             // [BH][DP][NSEQ]
  u16* y   = v + (size_t)BH*NSEQ*DP;             // [4096][768]

  convert_all<<<dim3((XN8+WN8+PN8+255)/256), dim3(256), 0, stream>>>(x, qkv_w, proj_w, xb);
  zero_pads<<<dim3(512), dim3(256), 0, stream>>>(q, k, v);
  qkv_gemm<<<dim3(MROWS/128, N3C/128), dim3(256), 0, stream>>>(xb, wb, qkv_b, q, k, v);
  attn<<<dim3(BH, NSEQ/128), dim3(256), 0, stream>>>(q, k, v, y);
  proj_gemm<<<dim3(MROWS/64, CDIM/128), dim3(256), 0, stream>>>(y, pwb, proj_b, out);
}

// Round 8
// 185.010 us; speedup vs baseline: 1.0826x; 1.0826x over previous
//
#include <hip/hip_runtime.h>

typedef short v8s __attribute__((ext_vector_type(8)));
typedef short v4s __attribute__((ext_vector_type(4)));
typedef float v4f __attribute__((ext_vector_type(4)));
typedef unsigned short u16;

#define NSEQ 2048
#define CDIM 768
#define NH   16
#define DH   48
#define DP   64
#define MROWS 4096      // B*N
#define N3C  2304
#define BH   32         // B*H

#if __has_builtin(__builtin_amdgcn_exp2f)
#define EXP2(x) __builtin_amdgcn_exp2f(x)
#else
#define EXP2(x) exp2f(x)
#endif
#if __has_builtin(__builtin_amdgcn_rcpf)
#define RCP(x) __builtin_amdgcn_rcpf(x)
#else
#define RCP(x) (1.0f/(x))
#endif

__device__ __forceinline__ u16 f2bf(float f){
  unsigned u = __float_as_uint(f);
  u += 0x7FFFu + ((u>>16)&1u);      // RNE; inputs finite
  return (u16)(u>>16);
}

__device__ __forceinline__ void load_lds16(const u16* g, u16* l){
  __builtin_amdgcn_global_load_lds((const __attribute__((address_space(1))) void*)g,
                                   (__attribute__((address_space(3))) void*)l, 16, 0, 0);
}

// ---------------- K0: fused convert (x,qkv_w,proj_w -> bf16) + Q/K/V pad init ----------------
#define XN8  (MROWS*CDIM/8)                     // 393216
#define WN8  (N3C*CDIM/8)                       // 221184
#define PN8  (CDIM*CDIM/8)                      // 73728
#define CONVB ((XN8+WN8+PN8)/256)               // 2688 blocks
__global__ __launch_bounds__(256) void prep(const float* __restrict__ x, const float* __restrict__ w,
                                            const float* __restrict__ pw, u16* __restrict__ dst,
                                            u16* __restrict__ q, u16* __restrict__ k, u16* __restrict__ v){
  int bid = blockIdx.x;
  if (bid < CONVB){
    int i = bid*256 + threadIdx.x;
    const float* src;
    if (i < XN8)            src = x  + (size_t)i*8;
    else if (i < XN8+WN8)   src = w  + (size_t)(i - XN8)*8;
    else                    src = pw + (size_t)(i - XN8 - WN8)*8;
    v4f f0 = ((const v4f*)src)[0];
    v4f f1 = ((const v4f*)src)[1];
    v8s o;
#pragma unroll
    for (int j = 0; j < 4; j++) ((u16*)&o)[j]   = f2bf(f0[j]);
#pragma unroll
    for (int j = 0; j < 4; j++) ((u16*)&o)[4+j] = f2bf(f1[j]);
    ((v8s*)dst)[i] = o;
  } else {
    int idx = (bid - CONVB)*256 + threadIdx.x;  // 512 blocks -> 131072 threads
    v8s z = (v8s){0,0,0,0,0,0,0,0};
    int r = idx >> 1, half = idx & 1;           // Q/K: 65536 rows, 2x16B pad per row
    *(v8s*)(q + (size_t)r*DP + DH + half*8) = z;
    *(v8s*)(k + (size_t)r*DP + DH + half*8) = z;
    int bh = idx >> 12, i = idx & 4095;         // V: [bh][48..63][2048]
    int row = i >> 8, off = i & 255;
    const short one = (short)0x3F80;            // bf16 1.0
    v8s val = (row == 0) ? (v8s){one,one,one,one,one,one,one,one} : z;
    *(v8s*)(v + ((size_t)(bh*DP + DH + row))*NSEQ + off*8) = val;
  }
}

// ================= K1: qkv GEMM, m97 structure =================
__global__ __launch_bounds__(256) void qkv_gemm(const u16* __restrict__ x, const u16* __restrict__ w,
                                                const float* __restrict__ bias,
                                                u16* __restrict__ q, u16* __restrict__ k, u16* __restrict__ v){
  __shared__ __align__(16) u16 As[128*32];
  __shared__ __align__(16) u16 Bs[128*32];
  const int wave = threadIdx.x >> 6;
  const int lane = threadIdx.x & 63;
  const int l15  = lane & 15;
  const int quad = lane >> 4;
  const int wm = wave & 1, wn = wave >> 1;
  const int m0 = blockIdx.x*128, n0 = blockIdx.y*128;

  const int srow = lane >> 2;
  const int sg   = (lane & 3) ^ ((lane >> 3) & 3);
  const int sgoff = sg*8;

  v4f acc[4][4];
#pragma unroll
  for (int i = 0; i < 4; i++)
#pragma unroll
    for (int j = 0; j < 4; j++) acc[i][j] = (v4f){0.f,0.f,0.f,0.f};

  const int sig = (l15 >> 1) & 3;

  for (int kt = 0; kt < CDIM/32; kt++){
    const int k0 = kt*32;
    __syncthreads();
#pragma unroll
    for (int j = 0; j < 2; j++){
      int c = wave*2 + j;
      int r = c*16 + srow;
      load_lds16(x + (size_t)(m0 + r)*CDIM + k0 + sgoff, &As[c*512]);
      load_lds16(w + (size_t)(n0 + r)*CDIM + k0 + sgoff, &Bs[c*512]);
    }
    __syncthreads();

    v8s af[4], bf[4];
#pragma unroll
    for (int t = 0; t < 4; t++){
      int ra = wm*64 + t*16 + l15;
      af[t] = *(const v8s*)(&As[ra*32 + ((quad ^ sig)<<3)]);
      int rb = wn*64 + t*16 + l15;
      bf[t] = *(const v8s*)(&Bs[rb*32 + ((quad ^ sig)<<3)]);
    }
#pragma unroll
    for (int ti = 0; ti < 4; ti++)
#pragma unroll
      for (int tj = 0; tj < 4; tj++)
        acc[ti][tj] = __builtin_amdgcn_mfma_f32_16x16x32_bf16(af[ti], bf[tj], acc[ti][tj], 0, 0, 0);
  }

  const float QS = 0.2082540589f;   // 1/sqrt(48) * log2(e)
#pragma unroll
  for (int tj = 0; tj < 4; tj++){
    const int c = n0 + wn*64 + tj*16 + l15;
    const float bv = bias[c];
    const int t = c / CDIM;
    const int rem = c - t*CDIM;
    const int h = rem / DH;
    const int d = rem - h*DH;
#pragma unroll
    for (int ti = 0; ti < 4; ti++){
#pragma unroll
      for (int r = 0; r < 4; r++){
        int m = m0 + wm*64 + ti*16 + quad*4 + r;
        int b_ = m >> 11;
        int n  = m & (NSEQ-1);
        float val = acc[ti][tj][r] + bv;
        if (t == 0) val *= QS;
        u16 o  = f2bf(val);
        int bhn = b_*NH + h;
        if (t == 0)      q[((size_t)bhn*NSEQ + n)*DP + d] = o;
        else if (t == 1) k[((size_t)bhn*NSEQ + n)*DP + d] = o;
        else             v[((size_t)bhn*DP + d)*NSEQ + n] = o;
      }
    }
  }
}

// ---------------- K2: flash attention, K-split=2, fp32 additive partials ----------------
// No-max softmax => partial O and partial rowsum are purely additive across splits.
__global__ __launch_bounds__(256) void attn(const u16* __restrict__ q, const u16* __restrict__ k,
                                            const u16* __restrict__ v,
                                            float* __restrict__ oacc, float* __restrict__ lacc){
  __shared__ __align__(16) u16 Kl[64*64];       // [key][d], XOR-swizzled 16B granules
  __shared__ __align__(16) u16 Vl[64*64];       // [d][key], XOR-swizzled; d=48 row == 1.0
  __shared__ __align__(16) u16 Pl[4][16*64];    // per-wave P tile, XOR-swizzled
  const int bh = blockIdx.x;
  const int qt = blockIdx.y;
  const int sp = blockIdx.z;                    // key split 0/1
  const int wave = threadIdx.x >> 6;
  const int lane = threadIdx.x & 63;
  const int l15  = lane & 15;
  const int quad = lane >> 4;
  const u16* qb = q + (size_t)bh*NSEQ*DP;
  const u16* kb = k + (size_t)bh*NSEQ*DP;
  const u16* vb = v + (size_t)bh*DP*NSEQ;
  const int qm = qt*64 + wave*16;

  v8s qf[2];
#pragma unroll
  for (int ks = 0; ks < 2; ks++)
    qf[ks] = *(const v8s*)(qb + (size_t)(qm + l15)*DP + ks*32 + quad*8);

  v4f o[4];                      // dt 0..2 = output d-tiles; dt 3 col 0 = rowsum
#pragma unroll
  for (int i = 0; i < 4; i++) o[i] = (v4f){0.f,0.f,0.f,0.f};

  int pwoff[4][4];
#pragma unroll
  for (int nt = 0; nt < 4; nt++)
#pragma unroll
    for (int r = 0; r < 4; r++){
      int row = quad*4 + r;
      int col = nt*16 + l15;
      pwoff[nt][r] = row*64 + ((((col>>3) ^ (row&7))<<3) | (col&7));
    }

  for (int kt = sp*16; kt < sp*16 + 16; kt++){
    __syncthreads();
    {
      const int t = threadIdx.x;
#pragma unroll
      for (int p = 0; p < 2; p++){
        int ci  = t + p*256;
        int row = ci >> 3;
        int off = ci & 7;
        v8s kd = *(const v8s*)(kb + (size_t)(kt*64 + row)*DP + off*8);
        *(v8s*)(&Kl[row*64 + ((off ^ (row&7))<<3)]) = kd;
        v8s vd = *(const v8s*)(vb + (size_t)row*NSEQ + kt*64 + off*8);
        *(v8s*)(&Vl[row*64 + ((off ^ (row&7))<<3)]) = vd;
      }
    }
    __syncthreads();

    // S = Q K^T  (Q pre-scaled to log2 domain)
    v4f s[4];
#pragma unroll
    for (int nt = 0; nt < 4; nt++){
      s[nt] = (v4f){0.f,0.f,0.f,0.f};
#pragma unroll
      for (int ks = 0; ks < 2; ks++){
        int rrow = nt*16 + l15;
        v8s bf = *(const v8s*)(&Kl[rrow*64 + (((ks*4+quad) ^ (rrow&7))<<3)]);
        s[nt] = __builtin_amdgcn_mfma_f32_16x16x32_bf16(qf[ks], bf, s[nt], 0, 0, 0);
      }
    }

    // P = exp2(S) -> bf16 in LDS (no max, no reductions)
#pragma unroll
    for (int nt = 0; nt < 4; nt++)
#pragma unroll
      for (int r = 0; r < 4; r++)
        Pl[wave][pwoff[nt][r]] = f2bf(EXP2(s[nt][r]));

    // O += P V ; dt=3 (V row d=48 == 1.0) accumulates the rowsum in col 0
    v8s pa[2];
#pragma unroll
    for (int ks = 0; ks < 2; ks++){
      int ga = ks*4 + quad;
      pa[ks] = *(const v8s*)(&Pl[wave][l15*64 + ((ga ^ (l15&7))<<3)]);
    }
#pragma unroll
    for (int dt = 0; dt < 4; dt++){
#pragma unroll
      for (int ks = 0; ks < 2; ks++){
        int row = dt*16 + l15;
        v8s vf = *(const v8s*)(&Vl[row*64 + (((ks*4+quad) ^ (row&7))<<3)]);
        o[dt] = __builtin_amdgcn_mfma_f32_16x16x32_bf16(pa[ks], vf, o[dt], 0, 0, 0);
      }
    }
  }

  const int b_ = bh / NH, h = bh % NH;
  float* oa = oacc + (size_t)sp*MROWS*CDIM;
  float* la = lacc + (size_t)sp*MROWS*NH;
#pragma unroll
  for (int r = 0; r < 4; r++){
    int rowg = b_*NSEQ + qm + quad*4 + r;
#pragma unroll
    for (int dt = 0; dt < 3; dt++)
      oa[(size_t)rowg*CDIM + h*DH + dt*16 + l15] = o[dt][r];
    if (l15 == 0) la[rowg*NH + h] = o[3][r];    // rowsum lives at col 0 of dt=3
  }
}

// ---------------- K2b: combine splits, normalize, emit bf16 y ----------------
__global__ __launch_bounds__(256) void finalize(const float* __restrict__ oacc,
                                                const float* __restrict__ lacc,
                                                u16* __restrict__ y){
  int i = blockIdx.x*256 + threadIdx.x;         // 4096*192 threads, 4 cols each
  int rowg = i / 192, c4 = i - rowg*192;
  int c = c4*4, h = c / DH;                     // float4 never crosses an h block (48%4==0)
  float l = lacc[rowg*NH + h] + lacc[MROWS*NH + rowg*NH + h];
  float inv = RCP(l);
  v4f a = *(const v4f*)(oacc + (size_t)rowg*CDIM + c);
  v4f b = *(const v4f*)(oacc + (size_t)MROWS*CDIM + (size_t)rowg*CDIM + c);
  v4s o4;
#pragma unroll
  for (int j = 0; j < 4; j++) o4[j] = (short)f2bf((a[j] + b[j])*inv);
  *(v4s*)(y + (size_t)rowg*CDIM + c) = o4;
}

// ================= K3: proj GEMM, m97 structure, 64x128 tile =================
__global__ __launch_bounds__(256) void proj_gemm(const u16* __restrict__ y, const u16* __restrict__ w,
                                                 const float* __restrict__ bias, float* __restrict__ out){
  __shared__ __align__(16) u16 As[64*32];
  __shared__ __align__(16) u16 Bs[128*32];
  const int wave = threadIdx.x >> 6;
  const int lane = threadIdx.x & 63;
  const int l15  = lane & 15;
  const int quad = lane >> 4;
  const int wm = wave & 1, wn = wave >> 1;
  const int m0 = blockIdx.x*64, n0 = blockIdx.y*128;

  const int srow = lane >> 2;
  const int sg   = (lane & 3) ^ ((lane >> 3) & 3);
  const int sgoff = sg*8;

  v4f acc[2][4];
#pragma unroll
  for (int i = 0; i < 2; i++)
#pragma unroll
    for (int j = 0; j < 4; j++) acc[i][j] = (v4f){0.f,0.f,0.f,0.f};

  const int sig = (l15 >> 1) & 3;

  for (int kt = 0; kt < CDIM/32; kt++){
    const int k0 = kt*32;
    __syncthreads();
    {
      int rA = wave*16 + srow;
      load_lds16(y + (size_t)(m0 + rA)*CDIM + k0 + sgoff, &As[wave*512]);
#pragma unroll
      for (int j = 0; j < 2; j++){
        int c = wave*2 + j;
        int rB = c*16 + srow;
        load_lds16(w + (size_t)(n0 + rB)*CDIM + k0 + sgoff, &Bs[c*512]);
      }
    }
    __syncthreads();

    v8s af[2], bf[4];
#pragma unroll
    for (int t = 0; t < 2; t++){
      int ra = wm*32 + t*16 + l15;
      af[t] = *(const v8s*)(&As[ra*32 + ((quad ^ sig)<<3)]);
    }
#pragma unroll
    for (int t = 0; t < 4; t++){
      int rb = wn*64 + t*16 + l15;
      bf[t] = *(const v8s*)(&Bs[rb*32 + ((quad ^ sig)<<3)]);
    }
#pragma unroll
    for (int ti = 0; ti < 2; ti++)
#pragma unroll
      for (int tj = 0; tj < 4; tj++)
        acc[ti][tj] = __builtin_amdgcn_mfma_f32_16x16x32_bf16(af[ti], bf[tj], acc[ti][tj], 0, 0, 0);
  }

#pragma unroll
  for (int tj = 0; tj < 4; tj++){
    const int c = n0 + wn*64 + tj*16 + l15;
    const float bv = bias[c];
#pragma unroll
    for (int ti = 0; ti < 2; ti++){
#pragma unroll
      for (int r = 0; r < 4; r++){
        int m = m0 + wm*32 + ti*16 + quad*4 + r;
        out[(size_t)m*CDIM + c] = acc[ti][tj][r] + bv;
      }
    }
  }
}

extern "C" void kernel_launch(void* const* d_in, const int* in_sizes, int n_in,
                              void* d_out, int out_size, void* d_ws, size_t ws_size,
                              hipStream_t stream){
  const float* x      = (const float*)d_in[0];
  const float* qkv_w  = (const float*)d_in[1];
  const float* qkv_b  = (const float*)d_in[2];
  const float* proj_w = (const float*)d_in[3];
  const float* proj_b = (const float*)d_in[4];
  float* out = (float*)d_out;

  // ws layout (u16 units); y reuses xb's region (x dead after qkv)
  u16* xb  = (u16*)d_ws;                         // [4096][768] bf16, later y
  u16* wb  = xb  + (size_t)MROWS*CDIM;           // [2304][768] bf16
  u16* pwb = wb  + (size_t)N3C*CDIM;             // [768][768]  bf16
  u16* q   = pwb + (size_t)CDIM*CDIM;            // [BH][NSEQ][DP]
  u16* k   = q + (size_t)BH*NSEQ*DP;
  u16* v   = k + (size_t)BH*NSEQ*DP;             // [BH][DP][NSEQ]
  float* oacc = (float*)(v + (size_t)BH*NSEQ*DP);        // [2][4096][768] fp32
  float* lacc = oacc + (size_t)2*MROWS*CDIM;             // [2][4096][16]  fp32
  u16* y = xb;

  prep<<<dim3(CONVB + 512), dim3(256), 0, stream>>>(x, qkv_w, proj_w, xb, q, k, v);
  qkv_gemm<<<dim3(MROWS/128, N3C/128), dim3(256), 0, stream>>>(xb, wb, qkv_b, q, k, v);
  attn<<<dim3(BH, NSEQ/64, 2), dim3(256), 0, stream>>>(q, k, v, oacc, lacc);
  finalize<<<dim3(MROWS*192/256), dim3(256), 0, stream>>>(oacc, lacc, y);
  proj_gemm<<<dim3(MROWS/64, CDIM/128), dim3(256), 0, stream>>>(y, pwb, proj_b, out);
}

// Round 9
// 174.404 us; speedup vs baseline: 1.1485x; 1.0608x over previous
//
#include <hip/hip_runtime.h>

typedef short v8s __attribute__((ext_vector_type(8)));
typedef short v4s __attribute__((ext_vector_type(4)));
typedef float v4f __attribute__((ext_vector_type(4)));
typedef unsigned uint2v __attribute__((ext_vector_type(2)));
typedef unsigned short u16;

#define NSEQ 2048
#define CDIM 768
#define NH   16
#define DH   48
#define DP   64
#define MROWS 4096      // B*N
#define N3C  2304
#define BH   32         // B*H

#if __has_builtin(__builtin_amdgcn_exp2f)
#define EXP2(x) __builtin_amdgcn_exp2f(x)
#else
#define EXP2(x) exp2f(x)
#endif
#if __has_builtin(__builtin_amdgcn_rcpf)
#define RCP(x) __builtin_amdgcn_rcpf(x)
#else
#define RCP(x) (1.0f/(x))
#endif

__device__ __forceinline__ u16 f2bf(float f){
  unsigned u = __float_as_uint(f);
  u += 0x7FFFu + ((u>>16)&1u);      // RNE; inputs finite
  return (u16)(u>>16);
}
__device__ __forceinline__ unsigned pkbf(float a, float b){   // [lo=a, hi=b] bf16 pair, RNE
  unsigned x = __float_as_uint(a), y = __float_as_uint(b);
  x += 0x7FFFu + ((x>>16)&1u);
  y += 0x7FFFu + ((y>>16)&1u);
  return (x>>16) | (y & 0xFFFF0000u);
}

__device__ __forceinline__ void load_lds16(const u16* g, u16* l){
  __builtin_amdgcn_global_load_lds((const __attribute__((address_space(1))) void*)g,
                                   (__attribute__((address_space(3))) void*)l, 16, 0, 0);
}

// ---------------- K0: fused convert (x,qkv_w,proj_w -> bf16) + Q/K/V pad init ----------------
#define XN8  (MROWS*CDIM/8)                     // 393216
#define WN8  (N3C*CDIM/8)                       // 221184
#define PN8  (CDIM*CDIM/8)                      // 73728
#define CONVB ((XN8+WN8+PN8)/256)               // 2688 blocks
__global__ __launch_bounds__(256) void prep(const float* __restrict__ x, const float* __restrict__ w,
                                            const float* __restrict__ pw, u16* __restrict__ dst,
                                            u16* __restrict__ q, u16* __restrict__ k, u16* __restrict__ v){
  int bid = blockIdx.x;
  if (bid < CONVB){
    int i = bid*256 + threadIdx.x;
    const float* src;
    if (i < XN8)            src = x  + (size_t)i*8;
    else if (i < XN8+WN8)   src = w  + (size_t)(i - XN8)*8;
    else                    src = pw + (size_t)(i - XN8 - WN8)*8;
    v4f f0 = ((const v4f*)src)[0];
    v4f f1 = ((const v4f*)src)[1];
    v8s o;
#pragma unroll
    for (int j = 0; j < 4; j++) ((u16*)&o)[j]   = f2bf(f0[j]);
#pragma unroll
    for (int j = 0; j < 4; j++) ((u16*)&o)[4+j] = f2bf(f1[j]);
    ((v8s*)dst)[i] = o;
  } else {
    int idx = (bid - CONVB)*256 + threadIdx.x;  // 512 blocks -> 131072 threads
    v8s z = (v8s){0,0,0,0,0,0,0,0};
    int r = idx >> 1, half = idx & 1;           // Q/K: 65536 rows, 2x16B pad per row
    *(v8s*)(q + (size_t)r*DP + DH + half*8) = z;
    *(v8s*)(k + (size_t)r*DP + DH + half*8) = z;
  }
}

// ================= K1: qkv GEMM, m97 structure =================
__global__ __launch_bounds__(256) void qkv_gemm(const u16* __restrict__ x, const u16* __restrict__ w,
                                                const float* __restrict__ bias,
                                                u16* __restrict__ q, u16* __restrict__ k, u16* __restrict__ v){
  __shared__ __align__(16) u16 As[128*32];
  __shared__ __align__(16) u16 Bs[128*32];
  const int wave = threadIdx.x >> 6;
  const int lane = threadIdx.x & 63;
  const int l15  = lane & 15;
  const int quad = lane >> 4;
  const int wm = wave & 1, wn = wave >> 1;
  const int m0 = blockIdx.x*128, n0 = blockIdx.y*128;

  const int srow = lane >> 2;
  const int sg   = (lane & 3) ^ ((lane >> 3) & 3);
  const int sgoff = sg*8;

  v4f acc[4][4];
#pragma unroll
  for (int i = 0; i < 4; i++)
#pragma unroll
    for (int j = 0; j < 4; j++) acc[i][j] = (v4f){0.f,0.f,0.f,0.f};

  const int sig = (l15 >> 1) & 3;

  for (int kt = 0; kt < CDIM/32; kt++){
    const int k0 = kt*32;
    __syncthreads();
#pragma unroll
    for (int j = 0; j < 2; j++){
      int c = wave*2 + j;
      int r = c*16 + srow;
      load_lds16(x + (size_t)(m0 + r)*CDIM + k0 + sgoff, &As[c*512]);
      load_lds16(w + (size_t)(n0 + r)*CDIM + k0 + sgoff, &Bs[c*512]);
    }
    __syncthreads();

    v8s af[4], bf[4];
#pragma unroll
    for (int t = 0; t < 4; t++){
      int ra = wm*64 + t*16 + l15;
      af[t] = *(const v8s*)(&As[ra*32 + ((quad ^ sig)<<3)]);
      int rb = wn*64 + t*16 + l15;
      bf[t] = *(const v8s*)(&Bs[rb*32 + ((quad ^ sig)<<3)]);
    }
#pragma unroll
    for (int ti = 0; ti < 4; ti++)
#pragma unroll
      for (int tj = 0; tj < 4; tj++)
        acc[ti][tj] = __builtin_amdgcn_mfma_f32_16x16x32_bf16(af[ti], bf[tj], acc[ti][tj], 0, 0, 0);
  }

  const float QS = 0.2082540589f;   // 1/sqrt(48) * log2(e)
#pragma unroll
  for (int tj = 0; tj < 4; tj++){
    const int c = n0 + wn*64 + tj*16 + l15;
    const float bv = bias[c];
    const int t = c / CDIM;
    const int rem = c - t*CDIM;
    const int h = rem / DH;
    const int d = rem - h*DH;
#pragma unroll
    for (int ti = 0; ti < 4; ti++){
#pragma unroll
      for (int r = 0; r < 4; r++){
        int m = m0 + wm*64 + ti*16 + quad*4 + r;
        int b_ = m >> 11;
        int n  = m & (NSEQ-1);
        float val = acc[ti][tj][r] + bv;
        if (t == 0) val *= QS;
        u16 o  = f2bf(val);
        int bhn = b_*NH + h;
        if (t == 0)      q[((size_t)bhn*NSEQ + n)*DP + d] = o;
        else if (t == 1) k[((size_t)bhn*NSEQ + n)*DP + d] = o;
        else             v[((size_t)bhn*DP + d)*NSEQ + n] = o;
      }
    }
  }
}

// ---------------- K2: flash attention, LDS-lean ----------------
// S^T = K*Q^T (swapped operands -> P-writes are ds_write_b64), 2 Q-strips/wave,
// K-split=2, global_load_lds staging, constant ones-fragment for the rowsum tile.
__global__ __launch_bounds__(256) void attn(const u16* __restrict__ q, const u16* __restrict__ k,
                                            const u16* __restrict__ v,
                                            float* __restrict__ oacc, float* __restrict__ lacc){
  __shared__ __align__(16) u16 Kl[64*64];       // [key][d], XOR-swizzled 16B granules
  __shared__ __align__(16) u16 Vl[48*64];       // [d][key] rows 0..47, XOR-swizzled
  __shared__ __align__(16) u16 Pl[4*2*1024];    // per-wave, per-strip P tiles
  const int bh = blockIdx.x;
  const int qt = blockIdx.y;                    // 128-row Q tile
  const int sp = blockIdx.z;                    // key split 0/1
  const int wave = threadIdx.x >> 6;
  const int lane = threadIdx.x & 63;
  const int l15  = lane & 15;
  const int quad = lane >> 4;
  const int lo3  = l15 & 7;
  const u16* qb = q + (size_t)bh*NSEQ*DP;
  const u16* kb = k + (size_t)bh*NSEQ*DP;
  const u16* vb = v + (size_t)bh*DP*NSEQ;
  const int qm = qt*128 + wave*32;

  v8s qf[2][2];                                 // [strip][ks]
#pragma unroll
  for (int si = 0; si < 2; si++)
#pragma unroll
    for (int ks = 0; ks < 2; ks++)
      qf[si][ks] = *(const v8s*)(qb + (size_t)(qm + si*16 + l15)*DP + ks*32 + quad*8);

  // constant B-fragment for rowsum: V[key][d=48..63] row of ones at n==0
  const short one = (short)0x3F80;
  const v8s vones = (l15 == 0) ? (v8s){one,one,one,one,one,one,one,one}
                               : (v8s){0,0,0,0,0,0,0,0};

  v4f o[2][4];                   // [strip][dt]; dt3 col0 = rowsum
#pragma unroll
  for (int si = 0; si < 2; si++)
#pragma unroll
    for (int i = 0; i < 4; i++) o[si][i] = (v4f){0.f,0.f,0.f,0.f};

  // staging lane constants (source-column permutation for swizzled LDS layout)
  const int sr  = lane >> 3;                    // 0..7
  const int soff = ((lane & 7) ^ (sr & 7)) * 8; // permuted 16B granule
  u16* Plw = Pl + wave*2048;

  for (int kt = sp*16; kt < sp*16 + 16; kt++){
    __syncthreads();
    {
      // K: 64 rows (2 chunks of 32)
#pragma unroll
      for (int p = 0; p < 2; p++){
        int row = p*32 + wave*8 + sr;
        load_lds16(kb + ((size_t)(kt*64 + row))*DP + soff, &Kl[(p*32 + wave*8)*64]);
      }
      // V: rows 0..47
      {
        int row = wave*8 + sr;
        load_lds16(vb + (size_t)row*NSEQ + kt*64 + soff, &Vl[(wave*8)*64]);
      }
      if (wave < 2){
        int row = 32 + wave*8 + sr;
        load_lds16(vb + (size_t)row*NSEQ + kt*64 + soff, &Vl[(32 + wave*8)*64]);
      }
    }
    __syncthreads();

    // S^T = K Q^T, exp2, pack pairs, b64 P-writes
#pragma unroll
    for (int si = 0; si < 2; si++){
      v4f s[4];
#pragma unroll
      for (int nt = 0; nt < 4; nt++){
        s[nt] = (v4f){0.f,0.f,0.f,0.f};
#pragma unroll
        for (int ks = 0; ks < 2; ks++){
          int rrow = nt*16 + l15;
          v8s kf = *(const v8s*)(&Kl[rrow*64 + (((ks*4+quad) ^ lo3)<<3)]);
          s[nt] = __builtin_amdgcn_mfma_f32_16x16x32_bf16(kf, qf[si][ks], s[nt], 0, 0, 0);
        }
      }
#pragma unroll
      for (int nt = 0; nt < 4; nt++){
        // lane holds keys nt*16 + quad*4 + (0..3) of q-row l15
        uint2v pw;
        pw.x = pkbf(EXP2(s[nt][0]), EXP2(s[nt][1]));
        pw.y = pkbf(EXP2(s[nt][2]), EXP2(s[nt][3]));
        int g = nt*2 + (quad>>1);               // 16B granule of the key run
        *(uint2v*)(&Plw[si*1024 + l15*64 + ((g ^ lo3)<<3) + (quad&1)*4]) = pw;
      }
    }

    // O += P V  (V fragments shared by both strips); dt3 via constant ones-frag
    v8s pa[2][2];
#pragma unroll
    for (int si = 0; si < 2; si++)
#pragma unroll
      for (int ks = 0; ks < 2; ks++){
        int ga = ks*4 + quad;
        pa[si][ks] = *(const v8s*)(&Plw[si*1024 + l15*64 + ((ga ^ lo3)<<3)]);
      }
#pragma unroll
    for (int dt = 0; dt < 3; dt++){
#pragma unroll
      for (int ks = 0; ks < 2; ks++){
        int row = dt*16 + l15;
        v8s vf = *(const v8s*)(&Vl[row*64 + (((ks*4+quad) ^ lo3)<<3)]);
        o[0][dt] = __builtin_amdgcn_mfma_f32_16x16x32_bf16(pa[0][ks], vf, o[0][dt], 0, 0, 0);
        o[1][dt] = __builtin_amdgcn_mfma_f32_16x16x32_bf16(pa[1][ks], vf, o[1][dt], 0, 0, 0);
      }
    }
#pragma unroll
    for (int ks = 0; ks < 2; ks++){
      o[0][3] = __builtin_amdgcn_mfma_f32_16x16x32_bf16(pa[0][ks], vones, o[0][3], 0, 0, 0);
      o[1][3] = __builtin_amdgcn_mfma_f32_16x16x32_bf16(pa[1][ks], vones, o[1][3], 0, 0, 0);
    }
  }

  const int b_ = bh / NH, h = bh % NH;
  float* oa = oacc + (size_t)sp*MROWS*CDIM;
  float* la = lacc + (size_t)sp*MROWS*NH;
#pragma unroll
  for (int si = 0; si < 2; si++){
#pragma unroll
    for (int r = 0; r < 4; r++){
      int rowg = b_*NSEQ + qm + si*16 + quad*4 + r;
#pragma unroll
      for (int dt = 0; dt < 3; dt++)
        oa[(size_t)rowg*CDIM + h*DH + dt*16 + l15] = o[si][dt][r];
      if (l15 == 0) la[rowg*NH + h] = o[si][3][r];  // rowsum at col 0 of dt3
    }
  }
}

// ---------------- K2b: combine splits, normalize, emit bf16 y ----------------
__global__ __launch_bounds__(256) void finalize(const float* __restrict__ oacc,
                                                const float* __restrict__ lacc,
                                                u16* __restrict__ y){
  int i = blockIdx.x*256 + threadIdx.x;         // 4096*192 threads, 4 cols each
  int rowg = i / 192, c4 = i - rowg*192;
  int c = c4*4, h = c / DH;                     // float4 never crosses an h block
  float l = lacc[rowg*NH + h] + lacc[MROWS*NH + rowg*NH + h];
  float inv = RCP(l);
  v4f a = *(const v4f*)(oacc + (size_t)rowg*CDIM + c);
  v4f b = *(const v4f*)(oacc + (size_t)MROWS*CDIM + (size_t)rowg*CDIM + c);
  v4s o4;
#pragma unroll
  for (int j = 0; j < 4; j++) o4[j] = (short)f2bf((a[j] + b[j])*inv);
  *(v4s*)(y + (size_t)rowg*CDIM + c) = o4;
}

// ================= K3: proj GEMM, m97 structure, 64x128 tile =================
__global__ __launch_bounds__(256) void proj_gemm(const u16* __restrict__ y, const u16* __restrict__ w,
                                                 const float* __restrict__ bias, float* __restrict__ out){
  __shared__ __align__(16) u16 As[64*32];
  __shared__ __align__(16) u16 Bs[128*32];
  const int wave = threadIdx.x >> 6;
  const int lane = threadIdx.x & 63;
  const int l15  = lane & 15;
  const int quad = lane >> 4;
  const int wm = wave & 1, wn = wave >> 1;
  const int m0 = blockIdx.x*64, n0 = blockIdx.y*128;

  const int srow = lane >> 2;
  const int sg   = (lane & 3) ^ ((lane >> 3) & 3);
  const int sgoff = sg*8;

  v4f acc[2][4];
#pragma unroll
  for (int i = 0; i < 2; i++)
#pragma unroll
    for (int j = 0; j < 4; j++) acc[i][j] = (v4f){0.f,0.f,0.f,0.f};

  const int sig = (l15 >> 1) & 3;

  for (int kt = 0; kt < CDIM/32; kt++){
    const int k0 = kt*32;
    __syncthreads();
    {
      int rA = wave*16 + srow;
      load_lds16(y + (size_t)(m0 + rA)*CDIM + k0 + sgoff, &As[wave*512]);
#pragma unroll
      for (int j = 0; j < 2; j++){
        int c = wave*2 + j;
        int rB = c*16 + srow;
        load_lds16(w + (size_t)(n0 + rB)*CDIM + k0 + sgoff, &Bs[c*512]);
      }
    }
    __syncthreads();

    v8s af[2], bf[4];
#pragma unroll
    for (int t = 0; t < 2; t++){
      int ra = wm*32 + t*16 + l15;
      af[t] = *(const v8s*)(&As[ra*32 + ((quad ^ sig)<<3)]);
    }
#pragma unroll
    for (int t = 0; t < 4; t++){
      int rb = wn*64 + t*16 + l15;
      bf[t] = *(const v8s*)(&Bs[rb*32 + ((quad ^ sig)<<3)]);
    }
#pragma unroll
    for (int ti = 0; ti < 2; ti++)
#pragma unroll
      for (int tj = 0; tj < 4; tj++)
        acc[ti][tj] = __builtin_amdgcn_mfma_f32_16x16x32_bf16(af[ti], bf[tj], acc[ti][tj], 0, 0, 0);
  }

#pragma unroll
  for (int tj = 0; tj < 4; tj++){
    const int c = n0 + wn*64 + tj*16 + l15;
    const float bv = bias[c];
#pragma unroll
    for (int ti = 0; ti < 2; ti++){
#pragma unroll
      for (int r = 0; r < 4; r++){
        int m = m0 + wm*32 + ti*16 + quad*4 + r;
        out[(size_t)m*CDIM + c] = acc[ti][tj][r] + bv;
      }
    }
  }
}

extern "C" void kernel_launch(void* const* d_in, const int* in_sizes, int n_in,
                              void* d_out, int out_size, void* d_ws, size_t ws_size,
                              hipStream_t stream){
  const float* x      = (const float*)d_in[0];
  const float* qkv_w  = (const float*)d_in[1];
  const float* qkv_b  = (const float*)d_in[2];
  const float* proj_w = (const float*)d_in[3];
  const float* proj_b = (const float*)d_in[4];
  float* out = (float*)d_out;

  // ws layout (u16 units); y reuses xb's region (x dead after qkv)
  u16* xb  = (u16*)d_ws;                         // [4096][768] bf16, later y
  u16* wb  = xb  + (size_t)MROWS*CDIM;           // [2304][768] bf16
  u16* pwb = wb  + (size_t)N3C*CDIM;             // [768][768]  bf16
  u16* q   = pwb + (size_t)CDIM*CDIM;            // [BH][NSEQ][DP]
  u16* k   = q + (size_t)BH*NSEQ*DP;
  u16* v   = k + (size_t)BH*NSEQ*DP;             // [BH][DP][NSEQ]
  float* oacc = (float*)(v + (size_t)BH*NSEQ*DP);        // [2][4096][768] fp32
  float* lacc = oacc + (size_t)2*MROWS*CDIM;             // [2][4096][16]  fp32
  u16* y = xb;

  prep<<<dim3(CONVB + 512), dim3(256), 0, stream>>>(x, qkv_w, proj_w, xb, q, k, v);
  qkv_gemm<<<dim3(MROWS/128, N3C/128), dim3(256), 0, stream>>>(xb, wb, qkv_b, q, k, v);
  attn<<<dim3(BH, NSEQ/128, 2), dim3(256), 0, stream>>>(q, k, v, oacc, lacc);
  finalize<<<dim3(MROWS*192/256), dim3(256), 0, stream>>>(oacc, lacc, y);
  proj_gemm<<<dim3(MROWS/64, CDIM/128), dim3(256), 0, stream>>>(y, pwb, proj_b, out);
}